// Round 3
// baseline (398.587 us; speedup 1.0000x reference)
//
#include <hip/hip_runtime.h>

// B=8, C=64, N=2048, K=32, H=8, d=8. Inputs FLOAT32; output FLOAT32.
// R11: (a) select = per-lane bitonic pre-sort on u64 (value,idx) keys +
// head-pointer tournament (exact same ordering semantics as R10's proven
// loop; ~3.5x fewer issue slots). (b) gemm reads PRE-SPLIT bf16 planes
// (hi/mid/lo u16, written by prep into the idx+A1 regions, dead until
// select/attn) -> no in-loop bsplit VALU. Numerics identical to R10.

#define NN 2048

typedef __attribute__((ext_vector_type(8))) short bf16x8;
typedef __attribute__((ext_vector_type(8))) unsigned short u16x8;
typedef __attribute__((ext_vector_type(4))) float f32x4;

// Exact 3-way bf16 split of an f32 value (hi+mid+lo == x exactly).
__device__ inline void bsplit(float x, short& h, short& m, short& l)
{
    unsigned u  = __float_as_uint(x);
    unsigned hb = (u + 0x7FFFu + ((u >> 16) & 1u)) >> 16;
    float hf = __uint_as_float(hb << 16);
    float r1 = x - hf;                       // exact (Sterbenz)
    unsigned u1 = __float_as_uint(r1);
    unsigned mb = (u1 + 0x7FFFu + ((u1 >> 16) & 1u)) >> 16;
    float mf = __uint_as_float(mb << 16);
    float r2 = r1 - mf;                      // exact; <= 8 significant bits
    unsigned u2 = __float_as_uint(r2);
    unsigned lb = (u2 + 0x7FFFu + ((u2 >> 16) & 1u)) >> 16;
    h = (short)hb; m = (short)mb; l = (short)lb;
}

// ---------------------------------------------------------------- prep ------
// Per 32-point tile: xx = sum x^2; K/V projections (fp32, point-major);
// bf16 3-way split planes xh/xm/xl, layout [b][n][c] u16.
__global__ __launch_bounds__(256) void prep_kernel(
    const float* __restrict__ x, const float* __restrict__ Wk,
    const float* __restrict__ Wv, float* __restrict__ xx,
    float* __restrict__ KT, float* __restrict__ VT,
    short* __restrict__ xh, short* __restrict__ xm, short* __restrict__ xl)
{
    __shared__ float xs[64][33];
    __shared__ float wks[4096], wvs[4096];
    const int t = threadIdx.x;
    const int b = blockIdx.x >> 6;
    const int n0 = (blockIdx.x & 63) * 32;
    for (int i = 0; i < 16; ++i) {
        int e = t + 256 * i;
        wks[e] = Wk[e];
        wvs[e] = Wv[e];
    }
    for (int i = 0; i < 8; ++i) {
        int e = t + 256 * i;
        xs[e >> 5][e & 31] = x[((size_t)b * 64 + (e >> 5)) * 2048 + n0 + (e & 31)];
    }
    __syncthreads();
    if (t < 32) {
        float s = 0.f;
#pragma unroll
        for (int c = 0; c < 64; ++c) { float v = xs[c][t]; s += v * v; }
        xx[b * 2048 + n0 + t] = s;
    }
    const int p = t & 31, g = t >> 5;
    {   // split planes: thread (p,g) -> channels [g*8, g*8+8) of point p
        u16x8 vh, vm, vl;
#pragma unroll
        for (int ci = 0; ci < 8; ++ci) {
            short h, m, l;
            bsplit(xs[g * 8 + ci][p], h, m, l);
            vh[ci] = (unsigned short)h; vm[ci] = (unsigned short)m; vl[ci] = (unsigned short)l;
        }
        size_t base = ((size_t)(b * 2048 + n0 + p)) * 64 + g * 8;
        *reinterpret_cast<u16x8*>(xh + base) = vh;
        *reinterpret_cast<u16x8*>(xm + base) = vm;
        *reinterpret_cast<u16x8*>(xl + base) = vl;
    }
    {   // K/V projections: 8 output channels per thread
        float xv[64];
#pragma unroll
        for (int c = 0; c < 64; ++c) xv[c] = xs[c][p];
        size_t base = ((size_t)(b * 2048 + n0 + p)) * 64 + g * 8;
        float ok[8], ov[8];
#pragma unroll
        for (int oi = 0; oi < 8; ++oi) {
            int o = g * 8 + oi;
            float ak = 0.f, av = 0.f;
#pragma unroll
            for (int c = 0; c < 64; ++c) {
                float xc = xv[c];
                ak += wks[o * 64 + c] * xc;
                av += wvs[o * 64 + c] * xc;
            }
            ok[oi] = ak; ov[oi] = av;
        }
        *reinterpret_cast<float4*>(KT + base)     = make_float4(ok[0], ok[1], ok[2], ok[3]);
        *reinterpret_cast<float4*>(KT + base + 4) = make_float4(ok[4], ok[5], ok[6], ok[7]);
        *reinterpret_cast<float4*>(VT + base)     = make_float4(ov[0], ov[1], ov[2], ov[3]);
        *reinterpret_cast<float4*>(VT + base + 4) = make_float4(ov[4], ov[5], ov[6], ov[7]);
    }
}

// ------------------------------------------------------------- knn gemm -----
// D'[b][n][m] = (2*G[n][m] - xx[n]) - xx[m], f32-precision via pre-split
// planes and 6 MFMA products (hh, hm, mh, hl, lh, mm). Fragment = one
// 16B load per plane ([n][c] layout, 8 consecutive channels).
__global__ __launch_bounds__(256) void gemm_kernel(
    const short* __restrict__ xh, const short* __restrict__ xm,
    const short* __restrict__ xl, const float* __restrict__ xx,
    float* __restrict__ Dp)
{
    const int t = threadIdx.x;
    const int lane = t & 63;
    const int w = t >> 6;
    const int b = blockIdx.x >> 8;
    const int tile = blockIdx.x & 255;
    const int r0 = (tile >> 4) * 128 + w * 32;  // wave's first row
    const int c0 = (tile & 15) * 128;           // block col base
    const int rl = lane & 15;                   // row/col within 16-block
    const int kg = (lane >> 4) * 8;             // k-group base (0,8,16,24)

    const size_t boff = (size_t)b * 2048 * 64;
    const short* XH = xh + boff;
    const short* XM = xm + boff;
    const short* XL = xl + boff;

    f32x4 acc[2][8];
#pragma unroll
    for (int rb = 0; rb < 2; ++rb)
#pragma unroll
        for (int cb = 0; cb < 8; ++cb)
            acc[rb][cb] = (f32x4){0.f, 0.f, 0.f, 0.f};

#pragma unroll
    for (int s = 0; s < 2; ++s) {               // channel slices 0..31, 32..63
        const int kb = s * 32 + kg;
        bf16x8 ah[2], am[2], al[2];
#pragma unroll
        for (int rb = 0; rb < 2; ++rb) {
            const size_t abase = (size_t)(r0 + rb * 16 + rl) * 64 + kb;
            ah[rb] = *reinterpret_cast<const bf16x8*>(XH + abase);
            am[rb] = *reinterpret_cast<const bf16x8*>(XM + abase);
            al[rb] = *reinterpret_cast<const bf16x8*>(XL + abase);
        }
#pragma unroll
        for (int cb = 0; cb < 8; ++cb) {
            const size_t bbase = (size_t)(c0 + cb * 16 + rl) * 64 + kb;
            bf16x8 bh = *reinterpret_cast<const bf16x8*>(XH + bbase);
            bf16x8 bm = *reinterpret_cast<const bf16x8*>(XM + bbase);
            bf16x8 bl = *reinterpret_cast<const bf16x8*>(XL + bbase);
#pragma unroll
            for (int rb = 0; rb < 2; ++rb) {
                f32x4 a = acc[rb][cb];
                a = __builtin_amdgcn_mfma_f32_16x16x32_bf16(al[rb], bh, a, 0, 0, 0);
                a = __builtin_amdgcn_mfma_f32_16x16x32_bf16(ah[rb], bl, a, 0, 0, 0);
                a = __builtin_amdgcn_mfma_f32_16x16x32_bf16(am[rb], bm, a, 0, 0, 0);
                a = __builtin_amdgcn_mfma_f32_16x16x32_bf16(am[rb], bh, a, 0, 0, 0);
                a = __builtin_amdgcn_mfma_f32_16x16x32_bf16(ah[rb], bm, a, 0, 0, 0);
                a = __builtin_amdgcn_mfma_f32_16x16x32_bf16(ah[rb], bh, a, 0, 0, 0);
                acc[rb][cb] = a;
            }
        }
    }

    // epilogue: C/D layout col=lane&15, row=(lane>>4)*4+reg  [m89-verified]
    const float* xxb = xx + b * 2048;
    const int rg = (lane >> 4) * 4;
#pragma unroll
    for (int cb = 0; cb < 8; ++cb) {
        const int col = c0 + cb * 16 + rl;
        const float xc = xxb[col];
#pragma unroll
        for (int rb = 0; rb < 2; ++rb) {
            const int rbase = r0 + rb * 16 + rg;
#pragma unroll
            for (int e = 0; e < 4; ++e) {
                float v = 2.f * acc[rb][cb][e] - xxb[rbase + e];  // (2G - xx_n)
                v = v - xc;                                       // ... - xx_m
                Dp[((size_t)(b * 2048 + rbase + e)) * 2048 + col] = v;
            }
        }
    }
}

// ------------------------------------------------------------ knn select ----
// Top-32 per row. 1 row per wave, 4 rows per block. Lane owns cols
// {q*256 + lane*4 + e} (coalesced loads). Keys u64 = (sortable_f32<<32) |
// (2047-idx): descending u64 order == (value desc, low-index tie-break),
// identical to the R10-proven loop. Per-lane bitonic sort (240 static CEs),
// sorted tails in LDS; each global iter = 6-step butterfly over lane heads
// + owner pops next from its LDS list.
__global__ __launch_bounds__(256) void select_kernel(
    const float* __restrict__ Dp, int* __restrict__ idx)
{
    __shared__ unsigned svs[4][32][64];        // [wave][entry][lane] 32 KiB
    __shared__ unsigned short ils[4][32][64];  // 16 KiB
    const int t = threadIdx.x, w = t >> 6, lane = t & 63;
    const int b = blockIdx.x >> 9;
    const int r = (blockIdx.x & 511) * 4 + w;
    const float* row = Dp + ((size_t)(b * 2048 + r)) * 2048;

    unsigned long long k[32];
#pragma unroll
    for (int q = 0; q < 8; ++q) {
        float4 f = *reinterpret_cast<const float4*>(row + q * 256 + lane * 4);
        float vv[4] = {f.x, f.y, f.z, f.w};
#pragma unroll
        for (int e = 0; e < 4; ++e) {
            unsigned u = __float_as_uint(vv[e]);
            unsigned sv = u ^ (unsigned)(((int)u >> 31) | 0x80000000);
            unsigned lo = 2047u - (unsigned)(q * 256 + lane * 4 + e);
            k[q * 4 + e] = ((unsigned long long)sv << 32) | lo;
        }
    }
    // bitonic sort, descending, 32 elems, all-static indices
#pragma unroll
    for (int kk = 2; kk <= 32; kk <<= 1) {
#pragma unroll
        for (int jj = kk >> 1; jj > 0; jj >>= 1) {
#pragma unroll
            for (int i = 0; i < 32; ++i) {
                int l = i ^ jj;
                if (l > i) {
                    unsigned long long a = k[i], c = k[l];
                    bool sw = ((i & kk) == 0) ? (a < c) : (a > c);
                    k[i] = sw ? c : a;
                    k[l] = sw ? a : c;
                }
            }
        }
    }
    // spill sorted lists (head stays in registers); wave-coherent, no barrier
#pragma unroll
    for (int j = 0; j < 32; ++j) {
        svs[w][j][lane] = (unsigned)(k[j] >> 32);
        ils[w][j][lane] = (unsigned short)(k[j] & 0xFFFFu);
    }
    unsigned hsv = (unsigned)(k[0] >> 32);
    unsigned hlo = (unsigned)(k[0] & 0xFFFFu);
    int p = 1;
    int* orow = idx + ((size_t)(b * 2048 + r)) * 32;
    for (int it = 0; it < 32; ++it) {
        unsigned bsv = hsv, blo = hlo;
#pragma unroll
        for (int d = 1; d < 64; d <<= 1) {
            unsigned osv = __shfl_xor(bsv, d);
            unsigned olo = __shfl_xor(blo, d);
            bool take = (osv > bsv) || (osv == bsv && olo > blo);
            bsv = take ? osv : bsv;
            blo = take ? olo : blo;
        }
        int gidx = 2047 - (int)blo;
        if (lane == ((gidx >> 2) & 63)) {  // owner pops its next entry
            int pp = p < 32 ? p : 31;
            unsigned ns = svs[w][pp][lane];
            unsigned nl = ils[w][pp][lane];
            hsv = (p < 32) ? ns : 0u;
            hlo = (p < 32) ? nl : 0u;
            ++p;
        }
        if (lane == 0) orow[it] = gidx;
    }
}

// ----------------------------------------------------- knn fallback ---------
// Old fused distances + top-32 (used only when ws_size can't hold D').
__global__ __launch_bounds__(256) void knn_kernel(
    const float* __restrict__ x, const float* __restrict__ xx,
    int* __restrict__ idx)
{
    __shared__ float Bs[64][65];
    __shared__ float As[4][65];
    __shared__ float xxs[2048];
    const int t = threadIdx.x, w = t >> 6, lane = t & 63;
    const int b = blockIdx.x >> 9;
    const int r0 = (blockIdx.x & 511) * 4;
    { int row = t >> 6, c = t & 63;
      As[row][c] = x[((size_t)b * 64 + c) * 2048 + r0 + row]; }
    for (int i = 0; i < 8; ++i) { int e = t + 256 * i; xxs[e] = xx[b * 2048 + e]; }
    const float xxr = xx[b * 2048 + r0 + w];
    float v[32];
    for (int jt = 0; jt < 32; ++jt) {
        __syncthreads();
        for (int i = 0; i < 16; ++i) {
            int e = t + 256 * i, c = e >> 6, p = e & 63;
            Bs[p][c] = x[((size_t)b * 64 + c) * 2048 + jt * 64 + p];
        }
        __syncthreads();
        float acc = 0.f;
#pragma unroll
        for (int c = 0; c < 64; ++c) acc += As[w][c] * Bs[lane][c];
        v[jt] = 2.f * acc - xxr - xxs[jt * 64 + lane];
    }
    unsigned mask = 0u;
    int* orow = idx + ((size_t)(b * 2048 + r0 + w)) * 32;
    for (int it = 0; it < 32; ++it) {
        float bv = -INFINITY; int bj = 0;
#pragma unroll
        for (int j = 0; j < 32; ++j) {
            bool ok = !((mask >> j) & 1u) && (v[j] > bv);
            bv = ok ? v[j] : bv;
            bj = ok ? j : bj;
        }
        int bi = bj * 64 + lane;
#pragma unroll
        for (int d = 1; d < 64; d <<= 1) {
            float ov = __shfl_xor(bv, d);
            int oi = __shfl_xor(bi, d);
            bool take = (ov > bv) || (ov == bv && oi < bi);
            bv = take ? ov : bv;
            bi = take ? oi : bi;
        }
        if (lane == (bi & 63)) mask |= 1u << (bi >> 6);
        if (lane == 0) orow[it] = bi;
    }
}

// ---------------------------------------------------------------- attn ------
// Per point: q = (Wq@x_n)/sqrt(8) on the fly; gather 32 neighbor K/V rows;
// energy = q.K[nbr] (the -q.K[n] term is softmax-invariant); serial softmax;
// out = sum a*V[nbr] - V[n] (sum a = 1). A1 = x + out, fp32 point-major.
__global__ __launch_bounds__(256) void attn_kernel(
    const float* __restrict__ x, const float* __restrict__ Wq,
    const float* __restrict__ KT, const float* __restrict__ VT,
    const int* __restrict__ idx, float* __restrict__ A1)
{
    __shared__ float wq[64][65];
    __shared__ int idxs[32];
    __shared__ float xq[64];
    __shared__ float qs[64];
    __shared__ float Kn[32][66], Vn[32][66];
    __shared__ float es[256], av[256];
    const int t = threadIdx.x;
    const int b = blockIdx.x >> 11;
    const int n = blockIdx.x & 2047;
    const size_t pbase = ((size_t)(b * 2048 + n)) * 64;
    if (t < 32) idxs[t] = idx[((size_t)(b * 2048 + n)) * 32 + t] & 2047;  // clamp
    else if (t < 96) xq[t - 32] = x[((size_t)b * 64 + (t - 32)) * 2048 + n];
    for (int i = 0; i < 16; ++i) {
        int e = t + 256 * i;
        wq[e >> 6][e & 63] = Wq[e];
    }
    __syncthreads();
    {   // gather K/V neighbor rows
        int j = t >> 3, c0 = (t & 7) * 8;
        size_t nb = ((size_t)(b * 2048 + idxs[j])) * 64 + c0;
        float4 ka = *reinterpret_cast<const float4*>(KT + nb);
        float4 kb = *reinterpret_cast<const float4*>(KT + nb + 4);
        float4 va = *reinterpret_cast<const float4*>(VT + nb);
        float4 vb = *reinterpret_cast<const float4*>(VT + nb + 4);
        Kn[j][c0 + 0] = ka.x; Kn[j][c0 + 1] = ka.y; Kn[j][c0 + 2] = ka.z; Kn[j][c0 + 3] = ka.w;
        Kn[j][c0 + 4] = kb.x; Kn[j][c0 + 5] = kb.y; Kn[j][c0 + 6] = kb.z; Kn[j][c0 + 7] = kb.w;
        Vn[j][c0 + 0] = va.x; Vn[j][c0 + 1] = va.y; Vn[j][c0 + 2] = va.z; Vn[j][c0 + 3] = va.w;
        Vn[j][c0 + 4] = vb.x; Vn[j][c0 + 5] = vb.y; Vn[j][c0 + 6] = vb.z; Vn[j][c0 + 7] = vb.w;
    }
    if (t < 64) {  // q = (Wq@x)/sqrt(8)
        float a = 0.f;
#pragma unroll
        for (int c = 0; c < 64; ++c) a += wq[t][c] * xq[c];
        qs[t] = a * 0.35355339059327379f;
    }
    __syncthreads();
    {
        int h = t >> 5, j = t & 31;
        float e = 0.f;
#pragma unroll
        for (int d = 0; d < 8; ++d) e += qs[h * 8 + d] * Kn[j][h * 8 + d];
        es[h * 32 + j] = e;
    }
    __syncthreads();
    if (t < 8) {  // serial per-head softmax (denominator >= 1)
        float mx = -INFINITY;
#pragma unroll
        for (int j = 0; j < 32; ++j) mx = fmaxf(mx, es[t * 32 + j]);
        float pv[32], s = 0.f;
#pragma unroll
        for (int j = 0; j < 32; ++j) { pv[j] = __expf(es[t * 32 + j] - mx); s += pv[j]; }
        float inv = 1.f / s;
#pragma unroll
        for (int j = 0; j < 32; ++j) av[t * 32 + j] = pv[j] * inv;
    }
    __syncthreads();
    if (t < 64) {
        int h = t >> 3;
        float acc = 0.f;
#pragma unroll
        for (int j = 0; j < 32; ++j) acc += av[h * 32 + j] * Vn[j][t];
        A1[pbase + t] = acc - VT[pbase + t] + xq[t];
    }
}

// ------------------------------------------------------------- BN stats -----
__global__ __launch_bounds__(256) void bn_partial_kernel(
    const float* __restrict__ Y, float* __restrict__ psum, float* __restrict__ psq)
{
    __shared__ float rs[4][64], rq[4][64];
    const int t = threadIdx.x;
    const int c = t & 63, pg = t >> 6;
    const int b = blockIdx.x >> 3;
    const int n0 = (blockIdx.x & 7) * 256;
    float s = 0.f, q = 0.f;
    for (int k = 0; k < 64; ++k) {
        float v = Y[((size_t)(b * 2048 + n0 + pg * 64 + k)) * 64 + c];
        s += v; q += v * v;
    }
    rs[pg][c] = s; rq[pg][c] = q;
    __syncthreads();
    if (t < 64) {
        psum[blockIdx.x * 64 + t] = rs[0][t] + rs[1][t] + rs[2][t] + rs[3][t];
        psq[blockIdx.x * 64 + t]  = rq[0][t] + rq[1][t] + rq[2][t] + rq[3][t];
    }
}

__global__ void bn_final_kernel(
    const float* __restrict__ psum, const float* __restrict__ psq,
    const float* __restrict__ gamma, const float* __restrict__ beta,
    float* __restrict__ sc, float* __restrict__ sh)
{
    int c = threadIdx.x;  // 64 threads
    float s = 0.f, q = 0.f;
    for (int i = 0; i < 64; ++i) { s += psum[i * 64 + c]; q += psq[i * 64 + c]; }
    float mean = s * (1.f / 16384.f);
    float var = q * (1.f / 16384.f) - mean * mean;
    float g = gamma[c] * rsqrtf(var + 1e-5f);
    sc[c] = g;
    sh[c] = beta[c] - mean * g;
}

// ------------------------------------------------------------ FFN fused -----
// Per 64-point tile: x1 = BN1(A1) -> h = leaky(W1@x1) (LDS) -> P2 = x1 + W2@h.
__global__ __launch_bounds__(256) void ffn_kernel(
    const float* __restrict__ A1, const float* __restrict__ W1,
    const float* __restrict__ W2, const float* __restrict__ s1,
    const float* __restrict__ t1, float* __restrict__ P2)
{
    __shared__ float W1s[8192];
    __shared__ float W2s[8192];
    __shared__ float xs[64][65];
    __shared__ float hs[64][129];
    __shared__ float sts[64], stt[64];
    const int t = threadIdx.x;
    const int b = blockIdx.x >> 5;
    const int n0 = (blockIdx.x & 31) * 64;
    if (t < 64) { sts[t] = s1[t]; stt[t] = t1[t]; }
    for (int i = 0; i < 32; ++i) {
        int e = t + 256 * i;
        W1s[e] = W1[e];
        W2s[e] = W2[e];
    }
    __syncthreads();
    for (int i = 0; i < 16; ++i) {
        int e = t + 256 * i, p = e >> 6, c = e & 63;
        xs[p][c] = A1[((size_t)(b * 2048 + n0 + p)) * 64 + c] * sts[c] + stt[c];
    }
    __syncthreads();
    const int p = t & 63, g = t >> 6;
    {   // h: 32 channels per thread
        float xv[64];
#pragma unroll
        for (int c = 0; c < 64; ++c) xv[c] = xs[p][c];
        for (int u = 0; u < 32; ++u) {
            int j = g * 32 + u;
            float acc = 0.f;
#pragma unroll
            for (int c = 0; c < 64; ++c) acc += W1s[j * 64 + c] * xv[c];
            hs[p][j] = (acc > 0.f) ? acc : 0.2f * acc;  // LeakyReLU 0.2
        }
    }
    __syncthreads();
    {   // P2: 16 channels per thread
        float hv[128];
#pragma unroll
        for (int j = 0; j < 128; ++j) hv[j] = hs[p][j];
        const size_t pbase = ((size_t)(b * 2048 + n0 + p)) * 64 + g * 16;
        float o4[16];
#pragma unroll
        for (int oi = 0; oi < 16; ++oi) {
            int o = g * 16 + oi;
            float a = xs[p][o];  // residual x1
#pragma unroll
            for (int j = 0; j < 128; ++j) a += W2s[o * 128 + j] * hv[j];
            o4[oi] = a;
        }
#pragma unroll
        for (int q = 0; q < 4; ++q)
            *reinterpret_cast<float4*>(P2 + pbase + q * 4) =
                make_float4(o4[q * 4], o4[q * 4 + 1], o4[q * 4 + 2], o4[q * 4 + 3]);
    }
}

// ---------------------------------------------------------------- final -----
// out = BN2(P2), fp32, layout (B, C, N).
__global__ __launch_bounds__(256) void final_kernel(
    const float* __restrict__ P2, const float* __restrict__ s2,
    const float* __restrict__ t2, float* __restrict__ out)
{
    __shared__ float ts[64][65];
    __shared__ float sts[64], stt[64];
    const int t = threadIdx.x;
    const int b = blockIdx.x >> 5;
    const int n0 = (blockIdx.x & 31) * 64;
    if (t < 64) { sts[t] = s2[t]; stt[t] = t2[t]; }
    __syncthreads();
    for (int i = 0; i < 16; ++i) {
        int e = t + 256 * i, p = e >> 6, c = e & 63;
        ts[p][c] = P2[((size_t)(b * 2048 + n0 + p)) * 64 + c] * sts[c] + stt[c];
    }
    __syncthreads();
    const int c = t >> 2, p0 = (t & 3) * 16;
    float* dst = out + ((size_t)(b * 64 + c)) * 2048 + n0 + p0;
#pragma unroll
    for (int q = 0; q < 4; ++q)
        *reinterpret_cast<float4*>(dst + q * 4) =
            make_float4(ts[p0 + q * 4 + 0][c], ts[p0 + q * 4 + 1][c],
                        ts[p0 + q * 4 + 2][c], ts[p0 + q * 4 + 3][c]);
}

// ------------------------------------------------------- safe fallback ------
__global__ __launch_bounds__(256) void zero_kernel(float* __restrict__ out)
{
    reinterpret_cast<float4*>(out)[blockIdx.x * 256 + threadIdx.x] =
        make_float4(0.f, 0.f, 0.f, 0.f);  // 1024*256*16B = 4 MiB
}

// ---------------------------------------------------------------- launch ----
extern "C" void kernel_launch(void* const* d_in, const int* in_sizes, int n_in,
                              void* d_out, int out_size, void* d_ws, size_t ws_size,
                              hipStream_t stream)
{
    const float* x  = (const float*)d_in[0];
    const float* Wq = (const float*)d_in[1];
    const float* Wk = (const float*)d_in[2];
    const float* Wv = (const float*)d_in[3];
    const float* W1 = (const float*)d_in[4];
    const float* W2 = (const float*)d_in[5];
    const float* g1 = (const float*)d_in[6];
    const float* b1 = (const float*)d_in[7];
    const float* g2 = (const float*)d_in[8];
    const float* b2 = (const float*)d_in[9];
    float* out = (float*)d_out;
    (void)in_sizes; (void)n_in; (void)out_size;

    char* ws = (char*)d_ws;
    const size_t off_xx  = 0;                   // 64 KiB
    const size_t off_KT  = 65536;               // 4 MiB fp32 (P2 overlays after attn)
    const size_t off_VT  = off_KT  + 4194304;   // 4 MiB
    const size_t off_idx = off_VT  + 4194304;   // 2 MiB int (xh plane before select)
    const size_t off_A1  = off_idx + 2097152;   // 4 MiB fp32 (xm+xl planes before attn)
    const size_t off_ps1 = off_A1  + 4194304;
    const size_t off_pq1 = off_ps1 + 16384;
    const size_t off_ps2 = off_pq1 + 16384;
    const size_t off_pq2 = off_ps2 + 16384;
    const size_t off_s1  = off_pq2 + 16384;
    const size_t off_t1  = off_s1 + 256;
    const size_t off_s2  = off_t1 + 256;
    const size_t off_t2  = off_s2 + 256;
    const size_t REQ_OLD = off_t2 + 256;        // ~14.1 MiB
    const size_t off_Dp  = 14815232;            // REQ_OLD rounded to 4 KiB
    const size_t DP_SZ   = (size_t)8 * 2048 * 2048 * 4;  // 128 MiB
    const size_t REQ_FAST = off_Dp + DP_SZ;     // ~142.2 MiB

    if (ws_size < REQ_OLD) {  // constant per capture: safe fail
        zero_kernel<<<1024, 256, 0, stream>>>(out);
        return;
    }

    float* xx = (float*)(ws + off_xx);
    float* KT = (float*)(ws + off_KT);
    float* VT = (float*)(ws + off_VT);
    int* idx  = (int*)(ws + off_idx);
    float* A1 = (float*)(ws + off_A1);
    float* P2 = KT;  // KT dead after attn
    // split planes: xh overlays idx (dead until select writes it);
    // xm/xl overlay A1 (dead until attn writes it). All consumed by gemm.
    short* xh = (short*)(ws + off_idx);
    short* xm = (short*)(ws + off_A1);
    short* xl = (short*)(ws + off_A1 + 2097152);
    float* ps1 = (float*)(ws + off_ps1); float* pq1 = (float*)(ws + off_pq1);
    float* ps2 = (float*)(ws + off_ps2); float* pq2 = (float*)(ws + off_pq2);
    float* s1 = (float*)(ws + off_s1); float* t1 = (float*)(ws + off_t1);
    float* s2 = (float*)(ws + off_s2); float* t2 = (float*)(ws + off_t2);
    float* Dp = (float*)(ws + off_Dp);

    prep_kernel<<<512, 256, 0, stream>>>(x, Wk, Wv, xx, KT, VT, xh, xm, xl);
    if (ws_size >= REQ_FAST) {
        gemm_kernel<<<2048, 256, 0, stream>>>(xh, xm, xl, xx, Dp);
        select_kernel<<<4096, 256, 0, stream>>>(Dp, idx);
    } else {
        knn_kernel<<<4096, 256, 0, stream>>>(x, xx, idx);
    }
    attn_kernel<<<16384, 256, 0, stream>>>(x, Wq, KT, VT, idx, A1);
    bn_partial_kernel<<<64, 256, 0, stream>>>(A1, ps1, pq1);
    bn_final_kernel<<<1, 64, 0, stream>>>(ps1, pq1, g1, b1, s1, t1);
    ffn_kernel<<<256, 256, 0, stream>>>(A1, W1, W2, s1, t1, P2);
    bn_partial_kernel<<<64, 256, 0, stream>>>(P2, ps2, pq2);
    bn_final_kernel<<<1, 64, 0, stream>>>(ps2, pq2, g2, b2, s2, t2);
    final_kernel<<<256, 256, 0, stream>>>(P2, s2, t2, out);
}

// Round 4
// 340.542 us; speedup vs baseline: 1.1704x; 1.1704x over previous
//
#include <hip/hip_runtime.h>

// B=8, C=64, N=2048, K=32, H=8, d=8. Inputs FLOAT32; output FLOAT32.
// R12: (a) select = exact threshold-compaction: per-lane max -> wave bitonic
// of 64 heads -> T = 32nd head; top-32 provably subset of {key >= T};
// compact (C<=64 typ.) -> one 64-lane bitonic -> done. R10-proven masked
// loop kept as exact fallback for C>64. LDS 48KB -> 2KB (occupancy fix).
// (b) gemm: sched_barrier(0) fences around each cb body to cap live
// B-fragments (R11 hoisted 48 loads -> spill). Math identical to R11.

#define NN 2048

typedef __attribute__((ext_vector_type(8))) short bf16x8;
typedef __attribute__((ext_vector_type(8))) unsigned short u16x8;
typedef __attribute__((ext_vector_type(4))) float f32x4;

// Exact 3-way bf16 split of an f32 value (hi+mid+lo == x exactly).
__device__ inline void bsplit(float x, short& h, short& m, short& l)
{
    unsigned u  = __float_as_uint(x);
    unsigned hb = (u + 0x7FFFu + ((u >> 16) & 1u)) >> 16;
    float hf = __uint_as_float(hb << 16);
    float r1 = x - hf;                       // exact (Sterbenz)
    unsigned u1 = __float_as_uint(r1);
    unsigned mb = (u1 + 0x7FFFu + ((u1 >> 16) & 1u)) >> 16;
    float mf = __uint_as_float(mb << 16);
    float r2 = r1 - mf;                      // exact; <= 8 significant bits
    unsigned u2 = __float_as_uint(r2);
    unsigned lb = (u2 + 0x7FFFu + ((u2 >> 16) & 1u)) >> 16;
    h = (short)hb; m = (short)mb; l = (short)lb;
}

// ---------------------------------------------------------------- prep ------
// Per 32-point tile: xx = sum x^2; K/V projections (fp32, point-major);
// bf16 3-way split planes xh/xm/xl, layout [b][n][c] u16.
__global__ __launch_bounds__(256) void prep_kernel(
    const float* __restrict__ x, const float* __restrict__ Wk,
    const float* __restrict__ Wv, float* __restrict__ xx,
    float* __restrict__ KT, float* __restrict__ VT,
    short* __restrict__ xh, short* __restrict__ xm, short* __restrict__ xl)
{
    __shared__ float xs[64][33];
    __shared__ float wks[4096], wvs[4096];
    const int t = threadIdx.x;
    const int b = blockIdx.x >> 6;
    const int n0 = (blockIdx.x & 63) * 32;
    for (int i = 0; i < 16; ++i) {
        int e = t + 256 * i;
        wks[e] = Wk[e];
        wvs[e] = Wv[e];
    }
    for (int i = 0; i < 8; ++i) {
        int e = t + 256 * i;
        xs[e >> 5][e & 31] = x[((size_t)b * 64 + (e >> 5)) * 2048 + n0 + (e & 31)];
    }
    __syncthreads();
    if (t < 32) {
        float s = 0.f;
#pragma unroll
        for (int c = 0; c < 64; ++c) { float v = xs[c][t]; s += v * v; }
        xx[b * 2048 + n0 + t] = s;
    }
    const int p = t & 31, g = t >> 5;
    {   // split planes: thread (p,g) -> channels [g*8, g*8+8) of point p
        u16x8 vh, vm, vl;
#pragma unroll
        for (int ci = 0; ci < 8; ++ci) {
            short h, m, l;
            bsplit(xs[g * 8 + ci][p], h, m, l);
            vh[ci] = (unsigned short)h; vm[ci] = (unsigned short)m; vl[ci] = (unsigned short)l;
        }
        size_t base = ((size_t)(b * 2048 + n0 + p)) * 64 + g * 8;
        *reinterpret_cast<u16x8*>(xh + base) = vh;
        *reinterpret_cast<u16x8*>(xm + base) = vm;
        *reinterpret_cast<u16x8*>(xl + base) = vl;
    }
    {   // K/V projections: 8 output channels per thread
        float xv[64];
#pragma unroll
        for (int c = 0; c < 64; ++c) xv[c] = xs[c][p];
        size_t base = ((size_t)(b * 2048 + n0 + p)) * 64 + g * 8;
        float ok[8], ov[8];
#pragma unroll
        for (int oi = 0; oi < 8; ++oi) {
            int o = g * 8 + oi;
            float ak = 0.f, av = 0.f;
#pragma unroll
            for (int c = 0; c < 64; ++c) {
                float xc = xv[c];
                ak += wks[o * 64 + c] * xc;
                av += wvs[o * 64 + c] * xc;
            }
            ok[oi] = ak; ov[oi] = av;
        }
        *reinterpret_cast<float4*>(KT + base)     = make_float4(ok[0], ok[1], ok[2], ok[3]);
        *reinterpret_cast<float4*>(KT + base + 4) = make_float4(ok[4], ok[5], ok[6], ok[7]);
        *reinterpret_cast<float4*>(VT + base)     = make_float4(ov[0], ov[1], ov[2], ov[3]);
        *reinterpret_cast<float4*>(VT + base + 4) = make_float4(ov[4], ov[5], ov[6], ov[7]);
    }
}

// ------------------------------------------------------------- knn gemm -----
// D'[b][n][m] = (2*G[n][m] - xx[n]) - xx[m], f32-precision via pre-split
// planes and 6 MFMA products (order: lh, hl, mm, mh, hm, hh — same as R11).
__device__ inline void mm6(f32x4& a, bf16x8 Ah, bf16x8 Am, bf16x8 Al,
                           bf16x8 Bh, bf16x8 Bm, bf16x8 Bl)
{
    a = __builtin_amdgcn_mfma_f32_16x16x32_bf16(Al, Bh, a, 0, 0, 0);
    a = __builtin_amdgcn_mfma_f32_16x16x32_bf16(Ah, Bl, a, 0, 0, 0);
    a = __builtin_amdgcn_mfma_f32_16x16x32_bf16(Am, Bm, a, 0, 0, 0);
    a = __builtin_amdgcn_mfma_f32_16x16x32_bf16(Am, Bh, a, 0, 0, 0);
    a = __builtin_amdgcn_mfma_f32_16x16x32_bf16(Ah, Bm, a, 0, 0, 0);
    a = __builtin_amdgcn_mfma_f32_16x16x32_bf16(Ah, Bh, a, 0, 0, 0);
}

__global__ __launch_bounds__(256) void gemm_kernel(
    const short* __restrict__ xh, const short* __restrict__ xm,
    const short* __restrict__ xl, const float* __restrict__ xx,
    float* __restrict__ Dp)
{
    const int t = threadIdx.x;
    const int lane = t & 63;
    const int w = t >> 6;
    const int b = blockIdx.x >> 8;
    const int tile = blockIdx.x & 255;
    const int r0 = (tile >> 4) * 128 + w * 32;  // wave's first row
    const int c0 = (tile & 15) * 128;           // block col base
    const int rl = lane & 15;                   // row/col within 16-block
    const int kg = (lane >> 4) * 8;             // k-group base (0,8,16,24)

    const size_t boff = (size_t)b * 2048 * 64;
    const short* XH = xh + boff;
    const short* XM = xm + boff;
    const short* XL = xl + boff;

    // A fragments: [s][rb], 12 x 16B, resident for the whole kernel
    bf16x8 aH[2][2], aM[2][2], aL[2][2];
#pragma unroll
    for (int s = 0; s < 2; ++s)
#pragma unroll
        for (int rb = 0; rb < 2; ++rb) {
            const size_t ab = (size_t)(r0 + rb * 16 + rl) * 64 + s * 32 + kg;
            aH[s][rb] = *reinterpret_cast<const bf16x8*>(XH + ab);
            aM[s][rb] = *reinterpret_cast<const bf16x8*>(XM + ab);
            aL[s][rb] = *reinterpret_cast<const bf16x8*>(XL + ab);
        }

    f32x4 acc[2][8];
#pragma unroll
    for (int rb = 0; rb < 2; ++rb)
#pragma unroll
        for (int cb = 0; cb < 8; ++cb)
            acc[rb][cb] = (f32x4){0.f, 0.f, 0.f, 0.f};

    // one fenced group per cb: 6 B-loads live at a time, no hoist/spill
#define CB_BODY(cb) { \
    __builtin_amdgcn_sched_barrier(0); \
    const size_t bb = (size_t)(c0 + (cb) * 16 + rl) * 64 + kg; \
    bf16x8 Bh0 = *reinterpret_cast<const bf16x8*>(XH + bb); \
    bf16x8 Bm0 = *reinterpret_cast<const bf16x8*>(XM + bb); \
    bf16x8 Bl0 = *reinterpret_cast<const bf16x8*>(XL + bb); \
    bf16x8 Bh1 = *reinterpret_cast<const bf16x8*>(XH + bb + 32); \
    bf16x8 Bm1 = *reinterpret_cast<const bf16x8*>(XM + bb + 32); \
    bf16x8 Bl1 = *reinterpret_cast<const bf16x8*>(XL + bb + 32); \
    mm6(acc[0][cb], aH[0][0], aM[0][0], aL[0][0], Bh0, Bm0, Bl0); \
    mm6(acc[1][cb], aH[0][1], aM[0][1], aL[0][1], Bh0, Bm0, Bl0); \
    mm6(acc[0][cb], aH[1][0], aM[1][0], aL[1][0], Bh1, Bm1, Bl1); \
    mm6(acc[1][cb], aH[1][1], aM[1][1], aL[1][1], Bh1, Bm1, Bl1); \
}
    CB_BODY(0) CB_BODY(1) CB_BODY(2) CB_BODY(3)
    CB_BODY(4) CB_BODY(5) CB_BODY(6) CB_BODY(7)
#undef CB_BODY
    __builtin_amdgcn_sched_barrier(0);

    // epilogue: C/D layout col=lane&15, row=(lane>>4)*4+reg  [m89-verified]
    const float* xxb = xx + b * 2048;
    const int rg = (lane >> 4) * 4;
#pragma unroll
    for (int cb = 0; cb < 8; ++cb) {
        const int col = c0 + cb * 16 + rl;
        const float xc = xxb[col];
#pragma unroll
        for (int rb = 0; rb < 2; ++rb) {
            const int rbase = r0 + rb * 16 + rg;
#pragma unroll
            for (int e = 0; e < 4; ++e) {
                float v = 2.f * acc[rb][cb][e] - xxb[rbase + e];  // (2G - xx_n)
                v = v - xc;                                       // ... - xx_m
                Dp[((size_t)(b * 2048 + rbase + e)) * 2048 + col] = v;
            }
        }
    }
}

// ------------------------------------------------------------ knn select ----
// Full key = (sortable_f32 << 32) | (2047 - gidx): descending key order ==
// (value desc, low-index tie-break) — same semantics as the R10-proven loop.
__device__ inline unsigned long long sort64desc(unsigned long long v, int lane)
{
#pragma unroll
    for (int k = 2; k <= 64; k <<= 1) {
#pragma unroll
        for (int j = k >> 1; j > 0; j >>= 1) {
            unsigned long long o = (unsigned long long)__shfl_xor((long long)v, j);
            bool takeMax = (((lane & k) == 0) == ((lane & j) == 0));
            unsigned long long mx = v > o ? v : o;
            unsigned long long mn = v > o ? o : v;
            v = takeMax ? mx : mn;
        }
    }
    return v;
}

__global__ __launch_bounds__(256) void select_kernel(
    const float* __restrict__ Dp, int* __restrict__ idx)
{
    __shared__ unsigned long long cand[4][64];  // 2 KiB
    const int t = threadIdx.x, w = t >> 6, lane = t & 63;
    const int b = blockIdx.x >> 9;
    const int r = (blockIdx.x & 511) * 4 + w;
    const float* row = Dp + ((size_t)(b * 2048 + r)) * 2048;
    int* orow = idx + ((size_t)(b * 2048 + r)) * 32;

    // lane owns cols {q*256 + lane*4 + e}; keys as sortable u32
    unsigned sv[32];
#pragma unroll
    for (int q = 0; q < 8; ++q) {
        float4 f = *reinterpret_cast<const float4*>(row + q * 256 + lane * 4);
        float vv[4] = {f.x, f.y, f.z, f.w};
#pragma unroll
        for (int e = 0; e < 4; ++e) {
            unsigned u = __float_as_uint(vv[e]);
            sv[q * 4 + e] = u ^ (unsigned)(((int)u >> 31) | 0x80000000);
        }
    }
    const unsigned lobase = 2047u - (unsigned)(lane * 4);
    // lo(slot s) = lobase - ((s>>2)*256 + (s&3));  gidx = 2047 - lo

    // per-lane max over full key
    unsigned bsv = sv[0], blo = lobase;
#pragma unroll
    for (int s = 1; s < 32; ++s) {
        unsigned lo = lobase - (unsigned)(((s >> 2) << 8) + (s & 3));
        bool take = (sv[s] > bsv) || (sv[s] == bsv && lo > blo);
        bsv = take ? sv[s] : bsv;
        blo = take ? lo : blo;
    }
    // sort 64 heads, T = 32nd largest head key
    unsigned long long hk = ((unsigned long long)bsv << 32) | blo;
    unsigned long long hs = sort64desc(hk, lane);
    const unsigned long long Tkey = (unsigned long long)__shfl((long long)hs, 31);
    const unsigned Tsv = (unsigned)(Tkey >> 32);
    const unsigned Tlo = (unsigned)(Tkey & 0xFFFFFFFFu);

    // count candidates (key >= Tkey)
    int c = 0;
#pragma unroll
    for (int s = 0; s < 32; ++s) {
        unsigned lo = lobase - (unsigned)(((s >> 2) << 8) + (s & 3));
        bool ge = (sv[s] > Tsv) || (sv[s] == Tsv && lo >= Tlo);
        c += ge ? 1 : 0;
    }
    int pfx = c;
#pragma unroll
    for (int d = 1; d < 64; d <<= 1) {
        int o = __shfl_up(pfx, d);
        pfx += (lane >= d) ? o : 0;
    }
    const int total = __shfl(pfx, 63);   // >= 32 always
    int off = pfx - c;

    if (total <= 64) {  // wave-uniform branch
        if (lane >= total) cand[w][lane] = 0ull;  // pad (disjoint slots)
#pragma unroll
        for (int s = 0; s < 32; ++s) {
            unsigned lo = lobase - (unsigned)(((s >> 2) << 8) + (s & 3));
            bool ge = (sv[s] > Tsv) || (sv[s] == Tsv && lo >= Tlo);
            if (ge) cand[w][off++] = ((unsigned long long)sv[s] << 32) | lo;
        }
        asm volatile("s_waitcnt lgkmcnt(0)" ::: "memory");
        __builtin_amdgcn_sched_barrier(0);
        unsigned long long q = cand[w][lane];
        q = sort64desc(q, lane);
        if (lane < 32) orow[lane] = 2047 - (int)(q & 0xFFFFu);
    } else {
        // exact fallback: R10-proven masked-rescan tournament (rare)
        unsigned cons = 0u;
        for (int it = 0; it < 32; ++it) {
            unsigned b2 = 0u, l2 = 0u;
#pragma unroll
            for (int s = 0; s < 32; ++s) {
                unsigned lo = lobase - (unsigned)(((s >> 2) << 8) + (s & 3));
                bool ok = !((cons >> s) & 1u) &&
                          ((sv[s] > b2) || (sv[s] == b2 && lo > l2));
                b2 = ok ? sv[s] : b2;
                l2 = ok ? lo : l2;
            }
            unsigned wsv = b2, wlo = l2;
#pragma unroll
            for (int d = 1; d < 64; d <<= 1) {
                unsigned osv = __shfl_xor(wsv, d);
                unsigned olo = __shfl_xor(wlo, d);
                bool take = (osv > wsv) || (osv == wsv && olo > wlo);
                wsv = take ? osv : wsv;
                wlo = take ? olo : wlo;
            }
            int gidx = 2047 - (int)wlo;
            if (lane == ((gidx >> 2) & 63)) {
                int slot = ((gidx >> 8) << 2) | (gidx & 3);
                cons |= 1u << slot;
            }
            if (lane == 0) orow[it] = gidx;
        }
    }
}

// ----------------------------------------------------- knn fallback ---------
// Old fused distances + top-32 (used only when ws_size can't hold D').
__global__ __launch_bounds__(256) void knn_kernel(
    const float* __restrict__ x, const float* __restrict__ xx,
    int* __restrict__ idx)
{
    __shared__ float Bs[64][65];
    __shared__ float As[4][65];
    __shared__ float xxs[2048];
    const int t = threadIdx.x, w = t >> 6, lane = t & 63;
    const int b = blockIdx.x >> 9;
    const int r0 = (blockIdx.x & 511) * 4;
    { int row = t >> 6, c = t & 63;
      As[row][c] = x[((size_t)b * 64 + c) * 2048 + r0 + row]; }
    for (int i = 0; i < 8; ++i) { int e = t + 256 * i; xxs[e] = xx[b * 2048 + e]; }
    const float xxr = xx[b * 2048 + r0 + w];
    float v[32];
    for (int jt = 0; jt < 32; ++jt) {
        __syncthreads();
        for (int i = 0; i < 16; ++i) {
            int e = t + 256 * i, c = e >> 6, p = e & 63;
            Bs[p][c] = x[((size_t)b * 64 + c) * 2048 + jt * 64 + p];
        }
        __syncthreads();
        float acc = 0.f;
#pragma unroll
        for (int c = 0; c < 64; ++c) acc += As[w][c] * Bs[lane][c];
        v[jt] = 2.f * acc - xxr - xxs[jt * 64 + lane];
    }
    unsigned mask = 0u;
    int* orow = idx + ((size_t)(b * 2048 + r0 + w)) * 32;
    for (int it = 0; it < 32; ++it) {
        float bv = -INFINITY; int bj = 0;
#pragma unroll
        for (int j = 0; j < 32; ++j) {
            bool ok = !((mask >> j) & 1u) && (v[j] > bv);
            bv = ok ? v[j] : bv;
            bj = ok ? j : bj;
        }
        int bi = bj * 64 + lane;
#pragma unroll
        for (int d = 1; d < 64; d <<= 1) {
            float ov = __shfl_xor(bv, d);
            int oi = __shfl_xor(bi, d);
            bool take = (ov > bv) || (ov == bv && oi < bi);
            bv = take ? ov : bv;
            bi = take ? oi : bi;
        }
        if (lane == (bi & 63)) mask |= 1u << (bi >> 6);
        if (lane == 0) orow[it] = bi;
    }
}

// ---------------------------------------------------------------- attn ------
// Per point: q = (Wq@x_n)/sqrt(8) on the fly; gather 32 neighbor K/V rows;
// energy = q.K[nbr] (the -q.K[n] term is softmax-invariant); serial softmax;
// out = sum a*V[nbr] - V[n] (sum a = 1). A1 = x + out, fp32 point-major.
__global__ __launch_bounds__(256) void attn_kernel(
    const float* __restrict__ x, const float* __restrict__ Wq,
    const float* __restrict__ KT, const float* __restrict__ VT,
    const int* __restrict__ idx, float* __restrict__ A1)
{
    __shared__ float wq[64][65];
    __shared__ int idxs[32];
    __shared__ float xq[64];
    __shared__ float qs[64];
    __shared__ float Kn[32][66], Vn[32][66];
    __shared__ float es[256], av[256];
    const int t = threadIdx.x;
    const int b = blockIdx.x >> 11;
    const int n = blockIdx.x & 2047;
    const size_t pbase = ((size_t)(b * 2048 + n)) * 64;
    if (t < 32) idxs[t] = idx[((size_t)(b * 2048 + n)) * 32 + t] & 2047;  // clamp
    else if (t < 96) xq[t - 32] = x[((size_t)b * 64 + (t - 32)) * 2048 + n];
    for (int i = 0; i < 16; ++i) {
        int e = t + 256 * i;
        wq[e >> 6][e & 63] = Wq[e];
    }
    __syncthreads();
    {   // gather K/V neighbor rows
        int j = t >> 3, c0 = (t & 7) * 8;
        size_t nb = ((size_t)(b * 2048 + idxs[j])) * 64 + c0;
        float4 ka = *reinterpret_cast<const float4*>(KT + nb);
        float4 kb = *reinterpret_cast<const float4*>(KT + nb + 4);
        float4 va = *reinterpret_cast<const float4*>(VT + nb);
        float4 vb = *reinterpret_cast<const float4*>(VT + nb + 4);
        Kn[j][c0 + 0] = ka.x; Kn[j][c0 + 1] = ka.y; Kn[j][c0 + 2] = ka.z; Kn[j][c0 + 3] = ka.w;
        Kn[j][c0 + 4] = kb.x; Kn[j][c0 + 5] = kb.y; Kn[j][c0 + 6] = kb.z; Kn[j][c0 + 7] = kb.w;
        Vn[j][c0 + 0] = va.x; Vn[j][c0 + 1] = va.y; Vn[j][c0 + 2] = va.z; Vn[j][c0 + 3] = va.w;
        Vn[j][c0 + 4] = vb.x; Vn[j][c0 + 5] = vb.y; Vn[j][c0 + 6] = vb.z; Vn[j][c0 + 7] = vb.w;
    }
    if (t < 64) {  // q = (Wq@x)/sqrt(8)
        float a = 0.f;
#pragma unroll
        for (int c = 0; c < 64; ++c) a += wq[t][c] * xq[c];
        qs[t] = a * 0.35355339059327379f;
    }
    __syncthreads();
    {
        int h = t >> 5, j = t & 31;
        float e = 0.f;
#pragma unroll
        for (int d = 0; d < 8; ++d) e += qs[h * 8 + d] * Kn[j][h * 8 + d];
        es[h * 32 + j] = e;
    }
    __syncthreads();
    if (t < 8) {  // serial per-head softmax (denominator >= 1)
        float mx = -INFINITY;
#pragma unroll
        for (int j = 0; j < 32; ++j) mx = fmaxf(mx, es[t * 32 + j]);
        float pv[32], s = 0.f;
#pragma unroll
        for (int j = 0; j < 32; ++j) { pv[j] = __expf(es[t * 32 + j] - mx); s += pv[j]; }
        float inv = 1.f / s;
#pragma unroll
        for (int j = 0; j < 32; ++j) av[t * 32 + j] = pv[j] * inv;
    }
    __syncthreads();
    if (t < 64) {
        int h = t >> 3;
        float acc = 0.f;
#pragma unroll
        for (int j = 0; j < 32; ++j) acc += av[h * 32 + j] * Vn[j][t];
        A1[pbase + t] = acc - VT[pbase + t] + xq[t];
    }
}

// ------------------------------------------------------------- BN stats -----
__global__ __launch_bounds__(256) void bn_partial_kernel(
    const float* __restrict__ Y, float* __restrict__ psum, float* __restrict__ psq)
{
    __shared__ float rs[4][64], rq[4][64];
    const int t = threadIdx.x;
    const int c = t & 63, pg = t >> 6;
    const int b = blockIdx.x >> 3;
    const int n0 = (blockIdx.x & 7) * 256;
    float s = 0.f, q = 0.f;
    for (int k = 0; k < 64; ++k) {
        float v = Y[((size_t)(b * 2048 + n0 + pg * 64 + k)) * 64 + c];
        s += v; q += v * v;
    }
    rs[pg][c] = s; rq[pg][c] = q;
    __syncthreads();
    if (t < 64) {
        psum[blockIdx.x * 64 + t] = rs[0][t] + rs[1][t] + rs[2][t] + rs[3][t];
        psq[blockIdx.x * 64 + t]  = rq[0][t] + rq[1][t] + rq[2][t] + rq[3][t];
    }
}

__global__ void bn_final_kernel(
    const float* __restrict__ psum, const float* __restrict__ psq,
    const float* __restrict__ gamma, const float* __restrict__ beta,
    float* __restrict__ sc, float* __restrict__ sh)
{
    int c = threadIdx.x;  // 64 threads
    float s = 0.f, q = 0.f;
    for (int i = 0; i < 64; ++i) { s += psum[i * 64 + c]; q += psq[i * 64 + c]; }
    float mean = s * (1.f / 16384.f);
    float var = q * (1.f / 16384.f) - mean * mean;
    float g = gamma[c] * rsqrtf(var + 1e-5f);
    sc[c] = g;
    sh[c] = beta[c] - mean * g;
}

// ------------------------------------------------------------ FFN fused -----
// Per 64-point tile: x1 = BN1(A1) -> h = leaky(W1@x1) (LDS) -> P2 = x1 + W2@h.
__global__ __launch_bounds__(256) void ffn_kernel(
    const float* __restrict__ A1, const float* __restrict__ W1,
    const float* __restrict__ W2, const float* __restrict__ s1,
    const float* __restrict__ t1, float* __restrict__ P2)
{
    __shared__ float W1s[8192];
    __shared__ float W2s[8192];
    __shared__ float xs[64][65];
    __shared__ float hs[64][129];
    __shared__ float sts[64], stt[64];
    const int t = threadIdx.x;
    const int b = blockIdx.x >> 5;
    const int n0 = (blockIdx.x & 31) * 64;
    if (t < 64) { sts[t] = s1[t]; stt[t] = t1[t]; }
    for (int i = 0; i < 32; ++i) {
        int e = t + 256 * i;
        W1s[e] = W1[e];
        W2s[e] = W2[e];
    }
    __syncthreads();
    for (int i = 0; i < 16; ++i) {
        int e = t + 256 * i, p = e >> 6, c = e & 63;
        xs[p][c] = A1[((size_t)(b * 2048 + n0 + p)) * 64 + c] * sts[c] + stt[c];
    }
    __syncthreads();
    const int p = t & 63, g = t >> 6;
    {   // h: 32 channels per thread
        float xv[64];
#pragma unroll
        for (int c = 0; c < 64; ++c) xv[c] = xs[p][c];
        for (int u = 0; u < 32; ++u) {
            int j = g * 32 + u;
            float acc = 0.f;
#pragma unroll
            for (int c = 0; c < 64; ++c) acc += W1s[j * 64 + c] * xv[c];
            hs[p][j] = (acc > 0.f) ? acc : 0.2f * acc;  // LeakyReLU 0.2
        }
    }
    __syncthreads();
    {   // P2: 16 channels per thread
        float hv[128];
#pragma unroll
        for (int j = 0; j < 128; ++j) hv[j] = hs[p][j];
        const size_t pbase = ((size_t)(b * 2048 + n0 + p)) * 64 + g * 16;
        float o4[16];
#pragma unroll
        for (int oi = 0; oi < 16; ++oi) {
            int o = g * 16 + oi;
            float a = xs[p][o];  // residual x1
#pragma unroll
            for (int j = 0; j < 128; ++j) a += W2s[o * 128 + j] * hv[j];
            o4[oi] = a;
        }
#pragma unroll
        for (int q = 0; q < 4; ++q)
            *reinterpret_cast<float4*>(P2 + pbase + q * 4) =
                make_float4(o4[q * 4], o4[q * 4 + 1], o4[q * 4 + 2], o4[q * 4 + 3]);
    }
}

// ---------------------------------------------------------------- final -----
// out = BN2(P2), fp32, layout (B, C, N).
__global__ __launch_bounds__(256) void final_kernel(
    const float* __restrict__ P2, const float* __restrict__ s2,
    const float* __restrict__ t2, float* __restrict__ out)
{
    __shared__ float ts[64][65];
    __shared__ float sts[64], stt[64];
    const int t = threadIdx.x;
    const int b = blockIdx.x >> 5;
    const int n0 = (blockIdx.x & 31) * 64;
    if (t < 64) { sts[t] = s2[t]; stt[t] = t2[t]; }
    __syncthreads();
    for (int i = 0; i < 16; ++i) {
        int e = t + 256 * i, p = e >> 6, c = e & 63;
        ts[p][c] = P2[((size_t)(b * 2048 + n0 + p)) * 64 + c] * sts[c] + stt[c];
    }
    __syncthreads();
    const int c = t >> 2, p0 = (t & 3) * 16;
    float* dst = out + ((size_t)(b * 64 + c)) * 2048 + n0 + p0;
#pragma unroll
    for (int q = 0; q < 4; ++q)
        *reinterpret_cast<float4*>(dst + q * 4) =
            make_float4(ts[p0 + q * 4 + 0][c], ts[p0 + q * 4 + 1][c],
                        ts[p0 + q * 4 + 2][c], ts[p0 + q * 4 + 3][c]);
}

// ------------------------------------------------------- safe fallback ------
__global__ __launch_bounds__(256) void zero_kernel(float* __restrict__ out)
{
    reinterpret_cast<float4*>(out)[blockIdx.x * 256 + threadIdx.x] =
        make_float4(0.f, 0.f, 0.f, 0.f);  // 1024*256*16B = 4 MiB
}

// ---------------------------------------------------------------- launch ----
extern "C" void kernel_launch(void* const* d_in, const int* in_sizes, int n_in,
                              void* d_out, int out_size, void* d_ws, size_t ws_size,
                              hipStream_t stream)
{
    const float* x  = (const float*)d_in[0];
    const float* Wq = (const float*)d_in[1];
    const float* Wk = (const float*)d_in[2];
    const float* Wv = (const float*)d_in[3];
    const float* W1 = (const float*)d_in[4];
    const float* W2 = (const float*)d_in[5];
    const float* g1 = (const float*)d_in[6];
    const float* b1 = (const float*)d_in[7];
    const float* g2 = (const float*)d_in[8];
    const float* b2 = (const float*)d_in[9];
    float* out = (float*)d_out;
    (void)in_sizes; (void)n_in; (void)out_size;

    char* ws = (char*)d_ws;
    const size_t off_xx  = 0;                   // 64 KiB
    const size_t off_KT  = 65536;               // 4 MiB fp32 (P2 overlays after attn)
    const size_t off_VT  = off_KT  + 4194304;   // 4 MiB
    const size_t off_idx = off_VT  + 4194304;   // 2 MiB int (xh plane before select)
    const size_t off_A1  = off_idx + 2097152;   // 4 MiB fp32 (xm+xl planes before attn)
    const size_t off_ps1 = off_A1  + 4194304;
    const size_t off_pq1 = off_ps1 + 16384;
    const size_t off_ps2 = off_pq1 + 16384;
    const size_t off_pq2 = off_ps2 + 16384;
    const size_t off_s1  = off_pq2 + 16384;
    const size_t off_t1  = off_s1 + 256;
    const size_t off_s2  = off_t1 + 256;
    const size_t off_t2  = off_s2 + 256;
    const size_t REQ_OLD = off_t2 + 256;        // ~14.1 MiB
    const size_t off_Dp  = 14815232;            // REQ_OLD rounded to 4 KiB
    const size_t DP_SZ   = (size_t)8 * 2048 * 2048 * 4;  // 128 MiB
    const size_t REQ_FAST = off_Dp + DP_SZ;     // ~142.2 MiB

    if (ws_size < REQ_OLD) {  // constant per capture: safe fail
        zero_kernel<<<1024, 256, 0, stream>>>(out);
        return;
    }

    float* xx = (float*)(ws + off_xx);
    float* KT = (float*)(ws + off_KT);
    float* VT = (float*)(ws + off_VT);
    int* idx  = (int*)(ws + off_idx);
    float* A1 = (float*)(ws + off_A1);
    float* P2 = KT;  // KT dead after attn
    // split planes: xh overlays idx (dead until select writes it);
    // xm/xl overlay A1 (dead until attn writes it). All consumed by gemm.
    short* xh = (short*)(ws + off_idx);
    short* xm = (short*)(ws + off_A1);
    short* xl = (short*)(ws + off_A1 + 2097152);
    float* ps1 = (float*)(ws + off_ps1); float* pq1 = (float*)(ws + off_pq1);
    float* ps2 = (float*)(ws + off_ps2); float* pq2 = (float*)(ws + off_pq2);
    float* s1 = (float*)(ws + off_s1); float* t1 = (float*)(ws + off_t1);
    float* s2 = (float*)(ws + off_s2); float* t2 = (float*)(ws + off_t2);
    float* Dp = (float*)(ws + off_Dp);

    prep_kernel<<<512, 256, 0, stream>>>(x, Wk, Wv, xx, KT, VT, xh, xm, xl);
    if (ws_size >= REQ_FAST) {
        gemm_kernel<<<2048, 256, 0, stream>>>(xh, xm, xl, xx, Dp);
        select_kernel<<<4096, 256, 0, stream>>>(Dp, idx);
    } else {
        knn_kernel<<<4096, 256, 0, stream>>>(x, xx, idx);
    }
    attn_kernel<<<16384, 256, 0, stream>>>(x, Wq, KT, VT, idx, A1);
    bn_partial_kernel<<<64, 256, 0, stream>>>(A1, ps1, pq1);
    bn_final_kernel<<<1, 64, 0, stream>>>(ps1, pq1, g1, b1, s1, t1);
    ffn_kernel<<<256, 256, 0, stream>>>(A1, W1, W2, s1, t1, P2);
    bn_partial_kernel<<<64, 256, 0, stream>>>(P2, ps2, pq2);
    bn_final_kernel<<<1, 64, 0, stream>>>(ps2, pq2, g2, b2, s2, t2);
    final_kernel<<<256, 256, 0, stream>>>(P2, s2, t2, out);
}

// Round 5
// 305.941 us; speedup vs baseline: 1.3028x; 1.1131x over previous
//
#include <hip/hip_runtime.h>

// B=8, C=64, N=2048, K=32, H=8, d=8. Inputs FLOAT32; output FLOAT32.
// R13: (a) gemm: B panel staged in LDS (48KB, 16B-chunk XOR swizzle ->
// conflict-free ds_read_b128); removes 4x inter-wave B redundancy and the
// 300cy global latency behind each sched_barrier. MFMA order identical.
// (b) select: per-lane max via depth-5 tree (was 32-step serial chain);
// 512-thread blocks. Threshold-compaction semantics unchanged (exact for
// ANY genuine-value heads; compact/sort use full keys).

#define NN 2048

typedef __attribute__((ext_vector_type(8))) short bf16x8;
typedef __attribute__((ext_vector_type(8))) unsigned short u16x8;
typedef __attribute__((ext_vector_type(4))) float f32x4;

// Exact 3-way bf16 split of an f32 value (hi+mid+lo == x exactly).
__device__ inline void bsplit(float x, short& h, short& m, short& l)
{
    unsigned u  = __float_as_uint(x);
    unsigned hb = (u + 0x7FFFu + ((u >> 16) & 1u)) >> 16;
    float hf = __uint_as_float(hb << 16);
    float r1 = x - hf;                       // exact (Sterbenz)
    unsigned u1 = __float_as_uint(r1);
    unsigned mb = (u1 + 0x7FFFu + ((u1 >> 16) & 1u)) >> 16;
    float mf = __uint_as_float(mb << 16);
    float r2 = r1 - mf;                      // exact; <= 8 significant bits
    unsigned u2 = __float_as_uint(r2);
    unsigned lb = (u2 + 0x7FFFu + ((u2 >> 16) & 1u)) >> 16;
    h = (short)hb; m = (short)mb; l = (short)lb;
}

// ---------------------------------------------------------------- prep ------
// Per 32-point tile: xx = sum x^2; K/V projections (fp32, point-major);
// bf16 3-way split planes xh/xm/xl, layout [b][n][c] u16.
__global__ __launch_bounds__(256) void prep_kernel(
    const float* __restrict__ x, const float* __restrict__ Wk,
    const float* __restrict__ Wv, float* __restrict__ xx,
    float* __restrict__ KT, float* __restrict__ VT,
    short* __restrict__ xh, short* __restrict__ xm, short* __restrict__ xl)
{
    __shared__ float xs[64][33];
    __shared__ float wks[4096], wvs[4096];
    const int t = threadIdx.x;
    const int b = blockIdx.x >> 6;
    const int n0 = (blockIdx.x & 63) * 32;
    for (int i = 0; i < 16; ++i) {
        int e = t + 256 * i;
        wks[e] = Wk[e];
        wvs[e] = Wv[e];
    }
    for (int i = 0; i < 8; ++i) {
        int e = t + 256 * i;
        xs[e >> 5][e & 31] = x[((size_t)b * 64 + (e >> 5)) * 2048 + n0 + (e & 31)];
    }
    __syncthreads();
    if (t < 32) {
        float s = 0.f;
#pragma unroll
        for (int c = 0; c < 64; ++c) { float v = xs[c][t]; s += v * v; }
        xx[b * 2048 + n0 + t] = s;
    }
    const int p = t & 31, g = t >> 5;
    {   // split planes: thread (p,g) -> channels [g*8, g*8+8) of point p
        u16x8 vh, vm, vl;
#pragma unroll
        for (int ci = 0; ci < 8; ++ci) {
            short h, m, l;
            bsplit(xs[g * 8 + ci][p], h, m, l);
            vh[ci] = (unsigned short)h; vm[ci] = (unsigned short)m; vl[ci] = (unsigned short)l;
        }
        size_t base = ((size_t)(b * 2048 + n0 + p)) * 64 + g * 8;
        *reinterpret_cast<u16x8*>(xh + base) = vh;
        *reinterpret_cast<u16x8*>(xm + base) = vm;
        *reinterpret_cast<u16x8*>(xl + base) = vl;
    }
    {   // K/V projections: 8 output channels per thread
        float xv[64];
#pragma unroll
        for (int c = 0; c < 64; ++c) xv[c] = xs[c][p];
        size_t base = ((size_t)(b * 2048 + n0 + p)) * 64 + g * 8;
        float ok[8], ov[8];
#pragma unroll
        for (int oi = 0; oi < 8; ++oi) {
            int o = g * 8 + oi;
            float ak = 0.f, av = 0.f;
#pragma unroll
            for (int c = 0; c < 64; ++c) {
                float xc = xv[c];
                ak += wks[o * 64 + c] * xc;
                av += wvs[o * 64 + c] * xc;
            }
            ok[oi] = ak; ov[oi] = av;
        }
        *reinterpret_cast<float4*>(KT + base)     = make_float4(ok[0], ok[1], ok[2], ok[3]);
        *reinterpret_cast<float4*>(KT + base + 4) = make_float4(ok[4], ok[5], ok[6], ok[7]);
        *reinterpret_cast<float4*>(VT + base)     = make_float4(ov[0], ov[1], ov[2], ov[3]);
        *reinterpret_cast<float4*>(VT + base + 4) = make_float4(ov[4], ov[5], ov[6], ov[7]);
    }
}

// ------------------------------------------------------------- knn gemm -----
// D'[b][n][m] = (2*G[n][m] - xx[n]) - xx[m], f32-precision via pre-split
// planes and 6 MFMA products (order identical to R12: lh,hl,mm,mh,hm,hh).
__device__ inline void mm6(f32x4& a, bf16x8 Ah, bf16x8 Am, bf16x8 Al,
                           bf16x8 Bh, bf16x8 Bm, bf16x8 Bl)
{
    a = __builtin_amdgcn_mfma_f32_16x16x32_bf16(Al, Bh, a, 0, 0, 0);
    a = __builtin_amdgcn_mfma_f32_16x16x32_bf16(Ah, Bl, a, 0, 0, 0);
    a = __builtin_amdgcn_mfma_f32_16x16x32_bf16(Am, Bm, a, 0, 0, 0);
    a = __builtin_amdgcn_mfma_f32_16x16x32_bf16(Am, Bh, a, 0, 0, 0);
    a = __builtin_amdgcn_mfma_f32_16x16x32_bf16(Ah, Bm, a, 0, 0, 0);
    a = __builtin_amdgcn_mfma_f32_16x16x32_bf16(Ah, Bh, a, 0, 0, 0);
}

__global__ __launch_bounds__(256) void gemm_kernel(
    const short* __restrict__ xh, const short* __restrict__ xm,
    const short* __restrict__ xl, const float* __restrict__ xx,
    float* __restrict__ Dp)
{
    __shared__ short BhL[8192], BmL[8192], BlL[8192];  // 48 KiB
    const int t = threadIdx.x;
    const int lane = t & 63;
    const int w = t >> 6;
    const int b = blockIdx.x >> 8;
    const int tile = blockIdx.x & 255;
    const int r0 = (tile >> 4) * 128 + w * 32;  // wave's first row
    const int c0 = (tile & 15) * 128;           // block col base (shared!)
    const int rl = lane & 15;
    const int g = lane >> 4;
    const int kg = g * 8;

    const size_t boff = (size_t)b * 2048 * 64;
    const short* XH = xh + boff;
    const short* XM = xm + boff;
    const short* XL = xl + boff;

    // A fragments: per-lane 16B globals, resident all kernel (12 frags)
    bf16x8 aH[2][2], aM[2][2], aL[2][2];
#pragma unroll
    for (int s = 0; s < 2; ++s)
#pragma unroll
        for (int rb = 0; rb < 2; ++rb) {
            const size_t ab = (size_t)(r0 + rb * 16 + rl) * 64 + s * 32 + kg;
            aH[s][rb] = *reinterpret_cast<const bf16x8*>(XH + ab);
            aM[s][rb] = *reinterpret_cast<const bf16x8*>(XM + ab);
            aL[s][rb] = *reinterpret_cast<const bf16x8*>(XL + ab);
        }

    // stage B panel (cols c0..c0+127, 64 ch) -> LDS; 16B chunk id ci:
    // col = ci>>3, j = ci&7; swizzle j ^= col&7 (breaks the 128B-stride
    // same-bank pattern on the frag ds_reads -> 2-way = free).
    {
        const short* sH = XH + (size_t)c0 * 64;
        const short* sM = XM + (size_t)c0 * 64;
        const short* sL = XL + (size_t)c0 * 64;
#pragma unroll
        for (int i = 0; i < 4; ++i) {
            int ci = t + 256 * i;
            int col = ci >> 3, j = ci & 7;
            int d = col * 64 + ((j ^ (col & 7)) << 3);  // short index
            *reinterpret_cast<u16x8*>(BhL + d) = *reinterpret_cast<const u16x8*>(sH + ci * 8);
            *reinterpret_cast<u16x8*>(BmL + d) = *reinterpret_cast<const u16x8*>(sM + ci * 8);
            *reinterpret_cast<u16x8*>(BlL + d) = *reinterpret_cast<const u16x8*>(sL + ci * 8);
        }
    }
    __syncthreads();

    f32x4 acc[2][8];
#pragma unroll
    for (int rb = 0; rb < 2; ++rb)
#pragma unroll
        for (int cb = 0; cb < 8; ++cb)
            acc[rb][cb] = (f32x4){0.f, 0.f, 0.f, 0.f};

#pragma unroll
    for (int cb = 0; cb < 8; ++cb) {
        __builtin_amdgcn_sched_barrier(0);
        const int cl = cb * 16 + rl;
#pragma unroll
        for (int s = 0; s < 2; ++s) {
            const int d = cl * 64 + (((s * 4 + g) ^ (cl & 7)) << 3);
            bf16x8 Bh = *reinterpret_cast<const bf16x8*>(BhL + d);
            bf16x8 Bm = *reinterpret_cast<const bf16x8*>(BmL + d);
            bf16x8 Bl = *reinterpret_cast<const bf16x8*>(BlL + d);
            mm6(acc[0][cb], aH[s][0], aM[s][0], aL[s][0], Bh, Bm, Bl);
            mm6(acc[1][cb], aH[s][1], aM[s][1], aL[s][1], Bh, Bm, Bl);
        }
    }
    __builtin_amdgcn_sched_barrier(0);

    // epilogue: C/D layout col=lane&15, row=(lane>>4)*4+reg  [m89-verified]
    const float* xxb = xx + b * 2048;
    const int rg = g * 4;
#pragma unroll
    for (int cb = 0; cb < 8; ++cb) {
        const int col = c0 + cb * 16 + rl;
        const float xc = xxb[col];
#pragma unroll
        for (int rb = 0; rb < 2; ++rb) {
            const int rbase = r0 + rb * 16 + rg;
#pragma unroll
            for (int e = 0; e < 4; ++e) {
                float v = 2.f * acc[rb][cb][e] - xxb[rbase + e];  // (2G - xx_n)
                v = v - xc;                                       // ... - xx_m
                Dp[((size_t)(b * 2048 + rbase + e)) * 2048 + col] = v;
            }
        }
    }
}

// ------------------------------------------------------------ knn select ----
// Full key = (sortable_f32 << 32) | (2047 - gidx): descending key order ==
// (value desc, low-index tie-break) — same semantics as the R10-proven loop.
// Threshold T = 32nd-largest of the 64 per-lane heads (each a genuine row
// value) -> >=32 row keys >= T -> top-32 subset of {key >= T}; compaction
// and final sort use FULL keys, so exactness is independent of head
// tie-order. Per-lane head via depth-5 tree (ILP) instead of 32-step chain.
__device__ inline unsigned long long sort64desc(unsigned long long v, int lane)
{
#pragma unroll
    for (int k = 2; k <= 64; k <<= 1) {
#pragma unroll
        for (int j = k >> 1; j > 0; j >>= 1) {
            unsigned long long o = (unsigned long long)__shfl_xor((long long)v, j);
            bool takeMax = (((lane & k) == 0) == ((lane & j) == 0));
            unsigned long long mx = v > o ? v : o;
            unsigned long long mn = v > o ? o : v;
            v = takeMax ? mx : mn;
        }
    }
    return v;
}

__global__ __launch_bounds__(512) void select_kernel(
    const float* __restrict__ Dp, int* __restrict__ idx)
{
    __shared__ unsigned long long cand[8][64];  // 4 KiB
    const int t = threadIdx.x, w = t >> 6, lane = t & 63;
    const int b = blockIdx.x >> 8;
    const int r = (blockIdx.x & 255) * 8 + w;
    const float* row = Dp + ((size_t)(b * 2048 + r)) * 2048;
    int* orow = idx + ((size_t)(b * 2048 + r)) * 32;

    const unsigned lobase = 2047u - (unsigned)(lane * 4);
    // lo(slot s) = lobase - ((s>>2)*256 + (s&3));  gidx = 2047 - lo

    unsigned sv[32];
    unsigned qsv[8]; int qsl[8];
#pragma unroll
    for (int q = 0; q < 8; ++q) {
        float4 f = *reinterpret_cast<const float4*>(row + q * 256 + lane * 4);
        float vv[4] = {f.x, f.y, f.z, f.w};
#pragma unroll
        for (int e = 0; e < 4; ++e) {
            unsigned u = __float_as_uint(vv[e]);
            sv[q * 4 + e] = u ^ (unsigned)(((int)u >> 31) | 0x80000000);
        }
        // mini-tree 4->1; strict '>' keeps smaller e (= larger lo) on ties
        unsigned v01 = sv[q * 4 + 1] > sv[q * 4] ? sv[q * 4 + 1] : sv[q * 4];
        int      s01 = sv[q * 4 + 1] > sv[q * 4] ? 1 : 0;
        unsigned v23 = sv[q * 4 + 3] > sv[q * 4 + 2] ? sv[q * 4 + 3] : sv[q * 4 + 2];
        int      s23 = sv[q * 4 + 3] > sv[q * 4 + 2] ? 3 : 2;
        qsv[q] = v23 > v01 ? v23 : v01;
        qsl[q] = q * 4 + (v23 > v01 ? s23 : s01);
    }
    // tree over the 8 per-q partials (strict '>': any genuine value is a
    // valid head — exactness does not depend on tie order here)
#pragma unroll
    for (int n = 4; n >= 1; n >>= 1)
#pragma unroll
        for (int i = 0; i < n; ++i) {
            bool take = qsv[i + n] > qsv[i];
            qsv[i] = take ? qsv[i + n] : qsv[i];
            qsl[i] = take ? qsl[i + n] : qsl[i];
        }
    const unsigned bsv = qsv[0];
    const int bs = qsl[0];
    const unsigned blo = lobase - (unsigned)(((bs >> 2) << 8) + (bs & 3));

    // sort 64 heads (full keys), T = 32nd largest
    unsigned long long hk = ((unsigned long long)bsv << 32) | blo;
    unsigned long long hs = sort64desc(hk, lane);
    const unsigned long long Tkey = (unsigned long long)__shfl((long long)hs, 31);
    const unsigned Tsv = (unsigned)(Tkey >> 32);
    const unsigned Tlo = (unsigned)(Tkey & 0xFFFFFFFFu);

    // count candidates (full key >= Tkey)
    int c = 0;
#pragma unroll
    for (int s = 0; s < 32; ++s) {
        unsigned lo = lobase - (unsigned)(((s >> 2) << 8) + (s & 3));
        bool ge = (sv[s] > Tsv) || (sv[s] == Tsv && lo >= Tlo);
        c += ge ? 1 : 0;
    }
    int pfx = c;
#pragma unroll
    for (int d = 1; d < 64; d <<= 1) {
        int o = __shfl_up(pfx, d);
        pfx += (lane >= d) ? o : 0;
    }
    const int total = __shfl(pfx, 63);   // >= 32 always
    int off = pfx - c;

    if (total <= 64) {  // wave-uniform branch
        if (lane >= total) cand[w][lane] = 0ull;  // pad (disjoint slots)
#pragma unroll
        for (int s = 0; s < 32; ++s) {
            unsigned lo = lobase - (unsigned)(((s >> 2) << 8) + (s & 3));
            bool ge = (sv[s] > Tsv) || (sv[s] == Tsv && lo >= Tlo);
            if (ge) cand[w][off++] = ((unsigned long long)sv[s] << 32) | lo;
        }
        asm volatile("s_waitcnt lgkmcnt(0)" ::: "memory");
        __builtin_amdgcn_sched_barrier(0);
        unsigned long long q = cand[w][lane];
        q = sort64desc(q, lane);
        if (lane < 32) orow[lane] = 2047 - (int)(q & 0xFFFFu);
    } else {
        // exact fallback: R10-proven masked-rescan tournament (rare)
        unsigned cons = 0u;
        for (int it = 0; it < 32; ++it) {
            unsigned b2 = 0u, l2 = 0u;
#pragma unroll
            for (int s = 0; s < 32; ++s) {
                unsigned lo = lobase - (unsigned)(((s >> 2) << 8) + (s & 3));
                bool ok = !((cons >> s) & 1u) &&
                          ((sv[s] > b2) || (sv[s] == b2 && lo > l2));
                b2 = ok ? sv[s] : b2;
                l2 = ok ? lo : l2;
            }
            unsigned wsv = b2, wlo = l2;
#pragma unroll
            for (int d = 1; d < 64; d <<= 1) {
                unsigned osv = __shfl_xor(wsv, d);
                unsigned olo = __shfl_xor(wlo, d);
                bool take = (osv > wsv) || (osv == wsv && olo > wlo);
                wsv = take ? osv : wsv;
                wlo = take ? olo : wlo;
            }
            int gidx = 2047 - (int)wlo;
            if (lane == ((gidx >> 2) & 63)) {
                int slot = ((gidx >> 8) << 2) | (gidx & 3);
                cons |= 1u << slot;
            }
            if (lane == 0) orow[it] = gidx;
        }
    }
}

// ----------------------------------------------------- knn fallback ---------
// Old fused distances + top-32 (used only when ws_size can't hold D').
__global__ __launch_bounds__(256) void knn_kernel(
    const float* __restrict__ x, const float* __restrict__ xx,
    int* __restrict__ idx)
{
    __shared__ float Bs[64][65];
    __shared__ float As[4][65];
    __shared__ float xxs[2048];
    const int t = threadIdx.x, w = t >> 6, lane = t & 63;
    const int b = blockIdx.x >> 9;
    const int r0 = (blockIdx.x & 511) * 4;
    { int row = t >> 6, c = t & 63;
      As[row][c] = x[((size_t)b * 64 + c) * 2048 + r0 + row]; }
    for (int i = 0; i < 8; ++i) { int e = t + 256 * i; xxs[e] = xx[b * 2048 + e]; }
    const float xxr = xx[b * 2048 + r0 + w];
    float v[32];
    for (int jt = 0; jt < 32; ++jt) {
        __syncthreads();
        for (int i = 0; i < 16; ++i) {
            int e = t + 256 * i, c = e >> 6, p = e & 63;
            Bs[p][c] = x[((size_t)b * 64 + c) * 2048 + jt * 64 + p];
        }
        __syncthreads();
        float acc = 0.f;
#pragma unroll
        for (int c = 0; c < 64; ++c) acc += As[w][c] * Bs[lane][c];
        v[jt] = 2.f * acc - xxr - xxs[jt * 64 + lane];
    }
    unsigned mask = 0u;
    int* orow = idx + ((size_t)(b * 2048 + r0 + w)) * 32;
    for (int it = 0; it < 32; ++it) {
        float bv = -INFINITY; int bj = 0;
#pragma unroll
        for (int j = 0; j < 32; ++j) {
            bool ok = !((mask >> j) & 1u) && (v[j] > bv);
            bv = ok ? v[j] : bv;
            bj = ok ? j : bj;
        }
        int bi = bj * 64 + lane;
#pragma unroll
        for (int d = 1; d < 64; d <<= 1) {
            float ov = __shfl_xor(bv, d);
            int oi = __shfl_xor(bi, d);
            bool take = (ov > bv) || (ov == bv && oi < bi);
            bv = take ? ov : bv;
            bi = take ? oi : bi;
        }
        if (lane == (bi & 63)) mask |= 1u << (bi >> 6);
        if (lane == 0) orow[it] = bi;
    }
}

// ---------------------------------------------------------------- attn ------
// Per point: q = (Wq@x_n)/sqrt(8) on the fly; gather 32 neighbor K/V rows;
// energy = q.K[nbr] (the -q.K[n] term is softmax-invariant); serial softmax;
// out = sum a*V[nbr] - V[n] (sum a = 1). A1 = x + out, fp32 point-major.
__global__ __launch_bounds__(256) void attn_kernel(
    const float* __restrict__ x, const float* __restrict__ Wq,
    const float* __restrict__ KT, const float* __restrict__ VT,
    const int* __restrict__ idx, float* __restrict__ A1)
{
    __shared__ float wq[64][65];
    __shared__ int idxs[32];
    __shared__ float xq[64];
    __shared__ float qs[64];
    __shared__ float Kn[32][66], Vn[32][66];
    __shared__ float es[256], av[256];
    const int t = threadIdx.x;
    const int b = blockIdx.x >> 11;
    const int n = blockIdx.x & 2047;
    const size_t pbase = ((size_t)(b * 2048 + n)) * 64;
    if (t < 32) idxs[t] = idx[((size_t)(b * 2048 + n)) * 32 + t] & 2047;  // clamp
    else if (t < 96) xq[t - 32] = x[((size_t)b * 64 + (t - 32)) * 2048 + n];
    for (int i = 0; i < 16; ++i) {
        int e = t + 256 * i;
        wq[e >> 6][e & 63] = Wq[e];
    }
    __syncthreads();
    {   // gather K/V neighbor rows
        int j = t >> 3, c0 = (t & 7) * 8;
        size_t nb = ((size_t)(b * 2048 + idxs[j])) * 64 + c0;
        float4 ka = *reinterpret_cast<const float4*>(KT + nb);
        float4 kb = *reinterpret_cast<const float4*>(KT + nb + 4);
        float4 va = *reinterpret_cast<const float4*>(VT + nb);
        float4 vb = *reinterpret_cast<const float4*>(VT + nb + 4);
        Kn[j][c0 + 0] = ka.x; Kn[j][c0 + 1] = ka.y; Kn[j][c0 + 2] = ka.z; Kn[j][c0 + 3] = ka.w;
        Kn[j][c0 + 4] = kb.x; Kn[j][c0 + 5] = kb.y; Kn[j][c0 + 6] = kb.z; Kn[j][c0 + 7] = kb.w;
        Vn[j][c0 + 0] = va.x; Vn[j][c0 + 1] = va.y; Vn[j][c0 + 2] = va.z; Vn[j][c0 + 3] = va.w;
        Vn[j][c0 + 4] = vb.x; Vn[j][c0 + 5] = vb.y; Vn[j][c0 + 6] = vb.z; Vn[j][c0 + 7] = vb.w;
    }
    if (t < 64) {  // q = (Wq@x)/sqrt(8)
        float a = 0.f;
#pragma unroll
        for (int c = 0; c < 64; ++c) a += wq[t][c] * xq[c];
        qs[t] = a * 0.35355339059327379f;
    }
    __syncthreads();
    {
        int h = t >> 5, j = t & 31;
        float e = 0.f;
#pragma unroll
        for (int d = 0; d < 8; ++d) e += qs[h * 8 + d] * Kn[j][h * 8 + d];
        es[h * 32 + j] = e;
    }
    __syncthreads();
    if (t < 8) {  // serial per-head softmax (denominator >= 1)
        float mx = -INFINITY;
#pragma unroll
        for (int j = 0; j < 32; ++j) mx = fmaxf(mx, es[t * 32 + j]);
        float pv[32], s = 0.f;
#pragma unroll
        for (int j = 0; j < 32; ++j) { pv[j] = __expf(es[t * 32 + j] - mx); s += pv[j]; }
        float inv = 1.f / s;
#pragma unroll
        for (int j = 0; j < 32; ++j) av[t * 32 + j] = pv[j] * inv;
    }
    __syncthreads();
    if (t < 64) {
        int h = t >> 3;
        float acc = 0.f;
#pragma unroll
        for (int j = 0; j < 32; ++j) acc += av[h * 32 + j] * Vn[j][t];
        A1[pbase + t] = acc - VT[pbase + t] + xq[t];
    }
}

// ------------------------------------------------------------- BN stats -----
__global__ __launch_bounds__(256) void bn_partial_kernel(
    const float* __restrict__ Y, float* __restrict__ psum, float* __restrict__ psq)
{
    __shared__ float rs[4][64], rq[4][64];
    const int t = threadIdx.x;
    const int c = t & 63, pg = t >> 6;
    const int b = blockIdx.x >> 3;
    const int n0 = (blockIdx.x & 7) * 256;
    float s = 0.f, q = 0.f;
    for (int k = 0; k < 64; ++k) {
        float v = Y[((size_t)(b * 2048 + n0 + pg * 64 + k)) * 64 + c];
        s += v; q += v * v;
    }
    rs[pg][c] = s; rq[pg][c] = q;
    __syncthreads();
    if (t < 64) {
        psum[blockIdx.x * 64 + t] = rs[0][t] + rs[1][t] + rs[2][t] + rs[3][t];
        psq[blockIdx.x * 64 + t]  = rq[0][t] + rq[1][t] + rq[2][t] + rq[3][t];
    }
}

__global__ void bn_final_kernel(
    const float* __restrict__ psum, const float* __restrict__ psq,
    const float* __restrict__ gamma, const float* __restrict__ beta,
    float* __restrict__ sc, float* __restrict__ sh)
{
    int c = threadIdx.x;  // 64 threads
    float s = 0.f, q = 0.f;
    for (int i = 0; i < 64; ++i) { s += psum[i * 64 + c]; q += psq[i * 64 + c]; }
    float mean = s * (1.f / 16384.f);
    float var = q * (1.f / 16384.f) - mean * mean;
    float g = gamma[c] * rsqrtf(var + 1e-5f);
    sc[c] = g;
    sh[c] = beta[c] - mean * g;
}

// ------------------------------------------------------------ FFN fused -----
// Per 64-point tile: x1 = BN1(A1) -> h = leaky(W1@x1) (LDS) -> P2 = x1 + W2@h.
__global__ __launch_bounds__(256) void ffn_kernel(
    const float* __restrict__ A1, const float* __restrict__ W1,
    const float* __restrict__ W2, const float* __restrict__ s1,
    const float* __restrict__ t1, float* __restrict__ P2)
{
    __shared__ float W1s[8192];
    __shared__ float W2s[8192];
    __shared__ float xs[64][65];
    __shared__ float hs[64][129];
    __shared__ float sts[64], stt[64];
    const int t = threadIdx.x;
    const int b = blockIdx.x >> 5;
    const int n0 = (blockIdx.x & 31) * 64;
    if (t < 64) { sts[t] = s1[t]; stt[t] = t1[t]; }
    for (int i = 0; i < 32; ++i) {
        int e = t + 256 * i;
        W1s[e] = W1[e];
        W2s[e] = W2[e];
    }
    __syncthreads();
    for (int i = 0; i < 16; ++i) {
        int e = t + 256 * i, p = e >> 6, c = e & 63;
        xs[p][c] = A1[((size_t)(b * 2048 + n0 + p)) * 64 + c] * sts[c] + stt[c];
    }
    __syncthreads();
    const int p = t & 63, g = t >> 6;
    {   // h: 32 channels per thread
        float xv[64];
#pragma unroll
        for (int c = 0; c < 64; ++c) xv[c] = xs[p][c];
        for (int u = 0; u < 32; ++u) {
            int j = g * 32 + u;
            float acc = 0.f;
#pragma unroll
            for (int c = 0; c < 64; ++c) acc += W1s[j * 64 + c] * xv[c];
            hs[p][j] = (acc > 0.f) ? acc : 0.2f * acc;  // LeakyReLU 0.2
        }
    }
    __syncthreads();
    {   // P2: 16 channels per thread
        float hv[128];
#pragma unroll
        for (int j = 0; j < 128; ++j) hv[j] = hs[p][j];
        const size_t pbase = ((size_t)(b * 2048 + n0 + p)) * 64 + g * 16;
        float o4[16];
#pragma unroll
        for (int oi = 0; oi < 16; ++oi) {
            int o = g * 16 + oi;
            float a = xs[p][o];  // residual x1
#pragma unroll
            for (int j = 0; j < 128; ++j) a += W2s[o * 128 + j] * hv[j];
            o4[oi] = a;
        }
#pragma unroll
        for (int q = 0; q < 4; ++q)
            *reinterpret_cast<float4*>(P2 + pbase + q * 4) =
                make_float4(o4[q * 4], o4[q * 4 + 1], o4[q * 4 + 2], o4[q * 4 + 3]);
    }
}

// ---------------------------------------------------------------- final -----
// out = BN2(P2), fp32, layout (B, C, N).
__global__ __launch_bounds__(256) void final_kernel(
    const float* __restrict__ P2, const float* __restrict__ s2,
    const float* __restrict__ t2, float* __restrict__ out)
{
    __shared__ float ts[64][65];
    __shared__ float sts[64], stt[64];
    const int t = threadIdx.x;
    const int b = blockIdx.x >> 5;
    const int n0 = (blockIdx.x & 31) * 64;
    if (t < 64) { sts[t] = s2[t]; stt[t] = t2[t]; }
    __syncthreads();
    for (int i = 0; i < 16; ++i) {
        int e = t + 256 * i, p = e >> 6, c = e & 63;
        ts[p][c] = P2[((size_t)(b * 2048 + n0 + p)) * 64 + c] * sts[c] + stt[c];
    }
    __syncthreads();
    const int c = t >> 2, p0 = (t & 3) * 16;
    float* dst = out + ((size_t)(b * 64 + c)) * 2048 + n0 + p0;
#pragma unroll
    for (int q = 0; q < 4; ++q)
        *reinterpret_cast<float4*>(dst + q * 4) =
            make_float4(ts[p0 + q * 4 + 0][c], ts[p0 + q * 4 + 1][c],
                        ts[p0 + q * 4 + 2][c], ts[p0 + q * 4 + 3][c]);
}

// ------------------------------------------------------- safe fallback ------
__global__ __launch_bounds__(256) void zero_kernel(float* __restrict__ out)
{
    reinterpret_cast<float4*>(out)[blockIdx.x * 256 + threadIdx.x] =
        make_float4(0.f, 0.f, 0.f, 0.f);  // 1024*256*16B = 4 MiB
}

// ---------------------------------------------------------------- launch ----
extern "C" void kernel_launch(void* const* d_in, const int* in_sizes, int n_in,
                              void* d_out, int out_size, void* d_ws, size_t ws_size,
                              hipStream_t stream)
{
    const float* x  = (const float*)d_in[0];
    const float* Wq = (const float*)d_in[1];
    const float* Wk = (const float*)d_in[2];
    const float* Wv = (const float*)d_in[3];
    const float* W1 = (const float*)d_in[4];
    const float* W2 = (const float*)d_in[5];
    const float* g1 = (const float*)d_in[6];
    const float* b1 = (const float*)d_in[7];
    const float* g2 = (const float*)d_in[8];
    const float* b2 = (const float*)d_in[9];
    float* out = (float*)d_out;
    (void)in_sizes; (void)n_in; (void)out_size;

    char* ws = (char*)d_ws;
    const size_t off_xx  = 0;                   // 64 KiB
    const size_t off_KT  = 65536;               // 4 MiB fp32 (P2 overlays after attn)
    const size_t off_VT  = off_KT  + 4194304;   // 4 MiB
    const size_t off_idx = off_VT  + 4194304;   // 2 MiB int (xh plane before select)
    const size_t off_A1  = off_idx + 2097152;   // 4 MiB fp32 (xm+xl planes before attn)
    const size_t off_ps1 = off_A1  + 4194304;
    const size_t off_pq1 = off_ps1 + 16384;
    const size_t off_ps2 = off_pq1 + 16384;
    const size_t off_pq2 = off_ps2 + 16384;
    const size_t off_s1  = off_pq2 + 16384;
    const size_t off_t1  = off_s1 + 256;
    const size_t off_s2  = off_t1 + 256;
    const size_t off_t2  = off_s2 + 256;
    const size_t REQ_OLD = off_t2 + 256;        // ~14.1 MiB
    const size_t off_Dp  = 14815232;            // REQ_OLD rounded to 4 KiB
    const size_t DP_SZ   = (size_t)8 * 2048 * 2048 * 4;  // 128 MiB
    const size_t REQ_FAST = off_Dp + DP_SZ;     // ~142.2 MiB

    if (ws_size < REQ_OLD) {  // constant per capture: safe fail
        zero_kernel<<<1024, 256, 0, stream>>>(out);
        return;
    }

    float* xx = (float*)(ws + off_xx);
    float* KT = (float*)(ws + off_KT);
    float* VT = (float*)(ws + off_VT);
    int* idx  = (int*)(ws + off_idx);
    float* A1 = (float*)(ws + off_A1);
    float* P2 = KT;  // KT dead after attn
    // split planes: xh overlays idx (dead until select writes it);
    // xm/xl overlay A1 (dead until attn writes it). All consumed by gemm.
    short* xh = (short*)(ws + off_idx);
    short* xm = (short*)(ws + off_A1);
    short* xl = (short*)(ws + off_A1 + 2097152);
    float* ps1 = (float*)(ws + off_ps1); float* pq1 = (float*)(ws + off_pq1);
    float* ps2 = (float*)(ws + off_ps2); float* pq2 = (float*)(ws + off_pq2);
    float* s1 = (float*)(ws + off_s1); float* t1 = (float*)(ws + off_t1);
    float* s2 = (float*)(ws + off_s2); float* t2 = (float*)(ws + off_t2);
    float* Dp = (float*)(ws + off_Dp);

    prep_kernel<<<512, 256, 0, stream>>>(x, Wk, Wv, xx, KT, VT, xh, xm, xl);
    if (ws_size >= REQ_FAST) {
        gemm_kernel<<<2048, 256, 0, stream>>>(xh, xm, xl, xx, Dp);
        select_kernel<<<2048, 512, 0, stream>>>(Dp, idx);
    } else {
        knn_kernel<<<4096, 256, 0, stream>>>(x, xx, idx);
    }
    attn_kernel<<<16384, 256, 0, stream>>>(x, Wq, KT, VT, idx, A1);
    bn_partial_kernel<<<64, 256, 0, stream>>>(A1, ps1, pq1);
    bn_final_kernel<<<1, 64, 0, stream>>>(ps1, pq1, g1, b1, s1, t1);
    ffn_kernel<<<256, 256, 0, stream>>>(A1, W1, W2, s1, t1, P2);
    bn_partial_kernel<<<64, 256, 0, stream>>>(P2, ps2, pq2);
    bn_final_kernel<<<1, 64, 0, stream>>>(ps2, pq2, g2, b2, s2, t2);
    final_kernel<<<256, 256, 0, stream>>>(P2, s2, t2, out);
}